// Round 1
// baseline (140.386 us; speedup 1.0000x reference)
//
#include <hip/hip_runtime.h>

#define HW_N (512 * 512)          // pixels per image plane
#define BINS 64
#define BPI 64                    // blocks per image for big passes
#define TPB 256

struct ImgStats {
    double sumx[3];
    double sumy[3];
    unsigned int minx, maxx, miny, maxy;   // ordered-uint encoded gray min/max
    unsigned int histx[BINS];
    unsigned int histy[BINS];
};

__device__ __forceinline__ unsigned int f2ord(float f) {
    unsigned int u = __float_as_uint(f);
    return (u & 0x80000000u) ? ~u : (u | 0x80000000u);
}
__device__ __forceinline__ float ord2f(unsigned int u) {
    u = (u & 0x80000000u) ? (u ^ 0x80000000u) : ~u;
    return __uint_as_float(u);
}

__device__ __forceinline__ float grayf(float r, float g, float b) {
    return 0.299f * r + 0.587f * g + 0.114f * b;
}

__device__ __forceinline__ double waveSumD(double v) {
#pragma unroll
    for (int o = 32; o > 0; o >>= 1) v += __shfl_down(v, o);
    return v;
}
__device__ __forceinline__ float waveMinF(float v) {
#pragma unroll
    for (int o = 32; o > 0; o >>= 1) v = fminf(v, __shfl_down(v, o));
    return v;
}
__device__ __forceinline__ float waveMaxF(float v) {
#pragma unroll
    for (int o = 32; o > 0; o >>= 1) v = fmaxf(v, __shfl_down(v, o));
    return v;
}

__global__ void k_init(ImgStats* st, int B) {
    const int nwords = B * (int)(sizeof(ImgStats) / 4);
    unsigned int* w = (unsigned int*)st;
    for (int i = threadIdx.x; i < nwords; i += blockDim.x) w[i] = 0u;
    __syncthreads();
    for (int i = threadIdx.x; i < B * 2; i += blockDim.x) {
        int b = i >> 1;
        if (i & 1) st[b].miny = 0xFFFFFFFFu;
        else       st[b].minx = 0xFFFFFFFFu;
    }
}

__global__ __launch_bounds__(TPB) void k_reduce(const float* __restrict__ x,
                                                const float* __restrict__ y,
                                                ImgStats* __restrict__ st) {
    const int b   = blockIdx.x / BPI;
    const int sub = blockIdx.x % BPI;
    const int qPerBlock = (HW_N / 4) / BPI;      // float4 groups this block handles
    const int q0 = sub * qPerBlock;
    const size_t base = (size_t)b * 3 * HW_N;

    const float4* xr = (const float4*)(x + base);
    const float4* xg = (const float4*)(x + base + HW_N);
    const float4* xb = (const float4*)(x + base + 2 * HW_N);
    const float4* yr = (const float4*)(y + base);
    const float4* yg = (const float4*)(y + base + HW_N);
    const float4* yb = (const float4*)(y + base + 2 * HW_N);

    float s0 = 0.f, s1 = 0.f, s2 = 0.f;          // x channel sums
    float t0 = 0.f, t1 = 0.f, t2 = 0.f;          // y channel sums
    float mnx = 3.4e38f, mxx = -3.4e38f;
    float mny = 3.4e38f, mxy = -3.4e38f;

    for (int i = threadIdx.x; i < qPerBlock; i += TPB) {
        const int q = q0 + i;
        float4 r = xr[q], g = xg[q], bl = xb[q];
        s0 += (r.x + r.y) + (r.z + r.w);
        s1 += (g.x + g.y) + (g.z + g.w);
        s2 += (bl.x + bl.y) + (bl.z + bl.w);
        {
            float g0 = grayf(r.x, g.x, bl.x), g1 = grayf(r.y, g.y, bl.y);
            float g2 = grayf(r.z, g.z, bl.z), g3 = grayf(r.w, g.w, bl.w);
            mnx = fminf(mnx, fminf(fminf(g0, g1), fminf(g2, g3)));
            mxx = fmaxf(mxx, fmaxf(fmaxf(g0, g1), fmaxf(g2, g3)));
        }
        r = yr[q]; g = yg[q]; bl = yb[q];
        t0 += (r.x + r.y) + (r.z + r.w);
        t1 += (g.x + g.y) + (g.z + g.w);
        t2 += (bl.x + bl.y) + (bl.z + bl.w);
        {
            float g0 = grayf(r.x, g.x, bl.x), g1 = grayf(r.y, g.y, bl.y);
            float g2 = grayf(r.z, g.z, bl.z), g3 = grayf(r.w, g.w, bl.w);
            mny = fminf(mny, fminf(fminf(g0, g1), fminf(g2, g3)));
            mxy = fmaxf(mxy, fmaxf(fmaxf(g0, g1), fmaxf(g2, g3)));
        }
    }

    const int wave = threadIdx.x >> 6;
    const int lane = threadIdx.x & 63;
    __shared__ double shs[6][TPB / 64];
    __shared__ float  shmn[2][TPB / 64];
    __shared__ float  shmx[2][TPB / 64];

    double d;
    d = waveSumD((double)s0); if (!lane) shs[0][wave] = d;
    d = waveSumD((double)s1); if (!lane) shs[1][wave] = d;
    d = waveSumD((double)s2); if (!lane) shs[2][wave] = d;
    d = waveSumD((double)t0); if (!lane) shs[3][wave] = d;
    d = waveSumD((double)t1); if (!lane) shs[4][wave] = d;
    d = waveSumD((double)t2); if (!lane) shs[5][wave] = d;
    float f;
    f = waveMinF(mnx); if (!lane) shmn[0][wave] = f;
    f = waveMinF(mny); if (!lane) shmn[1][wave] = f;
    f = waveMaxF(mxx); if (!lane) shmx[0][wave] = f;
    f = waveMaxF(mxy); if (!lane) shmx[1][wave] = f;
    __syncthreads();

    if (threadIdx.x == 0) {
        atomicAdd(&st[b].sumx[0], shs[0][0] + shs[0][1] + shs[0][2] + shs[0][3]);
        atomicAdd(&st[b].sumx[1], shs[1][0] + shs[1][1] + shs[1][2] + shs[1][3]);
        atomicAdd(&st[b].sumx[2], shs[2][0] + shs[2][1] + shs[2][2] + shs[2][3]);
        atomicAdd(&st[b].sumy[0], shs[3][0] + shs[3][1] + shs[3][2] + shs[3][3]);
        atomicAdd(&st[b].sumy[1], shs[4][0] + shs[4][1] + shs[4][2] + shs[4][3]);
        atomicAdd(&st[b].sumy[2], shs[5][0] + shs[5][1] + shs[5][2] + shs[5][3]);
        float a;
        a = fminf(fminf(shmn[0][0], shmn[0][1]), fminf(shmn[0][2], shmn[0][3]));
        atomicMin(&st[b].minx, f2ord(a));
        a = fminf(fminf(shmn[1][0], shmn[1][1]), fminf(shmn[1][2], shmn[1][3]));
        atomicMin(&st[b].miny, f2ord(a));
        a = fmaxf(fmaxf(shmx[0][0], shmx[0][1]), fmaxf(shmx[0][2], shmx[0][3]));
        atomicMax(&st[b].maxx, f2ord(a));
        a = fmaxf(fmaxf(shmx[1][0], shmx[1][1]), fmaxf(shmx[1][2], shmx[1][3]));
        atomicMax(&st[b].maxy, f2ord(a));
    }
}

__global__ __launch_bounds__(TPB) void k_hist(const float* __restrict__ x,
                                              const float* __restrict__ y,
                                              ImgStats* __restrict__ st) {
    // per-wave privatized histograms: [2 sources][4 waves][64 bins] = 2 KiB
    __shared__ unsigned int lh[8][BINS];
    for (int i = threadIdx.x; i < 8 * BINS; i += TPB) ((unsigned int*)lh)[i] = 0u;

    const int b   = blockIdx.x / BPI;
    const int sub = blockIdx.x % BPI;

    const float mnx = ord2f(st[b].minx), mxx = ord2f(st[b].maxx);
    const float mny = ord2f(st[b].miny), mxy = ord2f(st[b].maxy);
    const float rgx = (mxx > mnx) ? (mxx - mnx) : 1.0f;
    const float rgy = (mxy > mny) ? (mxy - mny) : 1.0f;
    __syncthreads();

    const int qPerBlock = (HW_N / 4) / BPI;
    const int q0 = sub * qPerBlock;
    const size_t base = (size_t)b * 3 * HW_N;

    const float4* xr = (const float4*)(x + base);
    const float4* xg = (const float4*)(x + base + HW_N);
    const float4* xb = (const float4*)(x + base + 2 * HW_N);
    const float4* yr = (const float4*)(y + base);
    const float4* yg = (const float4*)(y + base + HW_N);
    const float4* yb = (const float4*)(y + base + 2 * HW_N);

    const int wave = threadIdx.x >> 6;
    unsigned int* hx = lh[wave];
    unsigned int* hy = lh[4 + wave];

    for (int i = threadIdx.x; i < qPerBlock; i += TPB) {
        const int q = q0 + i;
        float4 r = xr[q], g = xg[q], bl = xb[q];
        {
            float gv[4] = { grayf(r.x, g.x, bl.x), grayf(r.y, g.y, bl.y),
                            grayf(r.z, g.z, bl.z), grayf(r.w, g.w, bl.w) };
#pragma unroll
            for (int j = 0; j < 4; j++) {
                float t = ((gv[j] - mnx) / rgx) * 63.0f;   // match ref: div, *63, trunc, clip
                int id = (int)t;
                id = id < 0 ? 0 : (id > 63 ? 63 : id);
                atomicAdd(&hx[id], 1u);
            }
        }
        r = yr[q]; g = yg[q]; bl = yb[q];
        {
            float gv[4] = { grayf(r.x, g.x, bl.x), grayf(r.y, g.y, bl.y),
                            grayf(r.z, g.z, bl.z), grayf(r.w, g.w, bl.w) };
#pragma unroll
            for (int j = 0; j < 4; j++) {
                float t = ((gv[j] - mny) / rgy) * 63.0f;
                int id = (int)t;
                id = id < 0 ? 0 : (id > 63 ? 63 : id);
                atomicAdd(&hy[id], 1u);
            }
        }
    }
    __syncthreads();

    for (int i = threadIdx.x; i < 2 * BINS; i += TPB) {
        const int src = i >> 6, bin = i & 63;
        unsigned int v = lh[src * 4 + 0][bin] + lh[src * 4 + 1][bin] +
                         lh[src * 4 + 2][bin] + lh[src * 4 + 3][bin];
        if (v) atomicAdd(src ? &st[b].histy[bin] : &st[b].histx[bin], v);
    }
}

__global__ __launch_bounds__(1024) void k_final(const ImgStats* __restrict__ st,
                                                float* __restrict__ out, int B) {
    const int tid = threadIdx.x;
    double klt = 0.0, cbt = 0.0;

    for (int t = tid; t < B * BINS; t += 1024) {
        const int b = t >> 6, bin = t & 63;
        const ImgStats& s = st[b];
        const float mnx = ord2f(s.minx), mxx = ord2f(s.maxx);
        const float mny = ord2f(s.miny), mxy = ord2f(s.maxy);
        const float invN = 1.0f / (float)HW_N;               // 2^-18, exact
        const float xh = (mxx > mnx) ? (float)s.histx[bin] * invN : (1.0f / BINS);
        const float yh = (mxy > mny) ? (float)s.histy[bin] * invN : (1.0f / BINS);
        const float log_in = logf(xh + 1e-8f);
        const float ylogy = (yh > 0.0f) ? yh * logf(yh) : 0.0f;
        klt += (double)ylogy - (double)yh * (double)log_in;
    }

    for (int t = tid; t < B * 3; t += 1024) {
        const int b = t / 3, c = t % 3;
        const ImgStats& s = st[b];
        const double N = (double)HW_N;
        const double xb = (s.sumx[c] / N) /
                          ((s.sumx[0] + s.sumx[1] + s.sumx[2]) / N + 1e-8);
        const double yb = (s.sumy[c] / N) /
                          ((s.sumy[0] + s.sumy[1] + s.sumy[2]) / N + 1e-8);
        cbt += fabs(xb - yb);
    }

    __shared__ double skl[16], scb[16];
    const double kw = waveSumD(klt);
    const double cw = waveSumD(cbt);
    const int wave = tid >> 6, lane = tid & 63;
    if (!lane) { skl[wave] = kw; scb[wave] = cw; }
    __syncthreads();
    if (tid == 0) {
        double K = 0.0, C = 0.0;
        for (int i = 0; i < 16; i++) { K += skl[i]; C += scb[i]; }
        const double kl = K / (double)B;
        const double cb = C / (double)(B * 3);
        out[0] = (float)(10.0 * (cb + kl));
    }
}

extern "C" void kernel_launch(void* const* d_in, const int* in_sizes, int n_in,
                              void* d_out, int out_size, void* d_ws, size_t ws_size,
                              hipStream_t stream) {
    const float* x = (const float*)d_in[0];
    const float* y = (const float*)d_in[1];
    float* out = (float*)d_out;
    const int B = in_sizes[0] / (3 * HW_N);   // 16

    ImgStats* st = (ImgStats*)d_ws;           // needs B * 576 bytes (~9.2 KiB)

    k_init<<<1, 256, 0, stream>>>(st, B);
    k_reduce<<<B * BPI, TPB, 0, stream>>>(x, y, st);
    k_hist<<<B * BPI, TPB, 0, stream>>>(x, y, st);
    k_final<<<1, 1024, 0, stream>>>(st, out, B);
}